// Round 1
// baseline (387.528 us; speedup 1.0000x reference)
//
#include <hip/hip_runtime.h>
#include <hip/hip_bf16.h>

// GCN encoder: out = concat(h1, h2), h_l = relu(Dinv(A+I)Dinv (x@W_l) + b_l)
// Inputs: x[N,128], W1,W2[128,128], b1,b2[128] = float32; edge_index int32 [2,E]
// Output: float32 [N,256] (harness compares vs bf16-emulated np ref, 2% rel).
//
// Round 6: agg_k memory-path tuning.
//  - 4 gather rows in flight per 16-lane group (was 2): the mean slot count
//    per group is ~4.25, so most nodes now issue their whole neighbor window
//    in one shot; kills a serialized col->G round trip for half the groups.
//  - Non-temporal stores for Out/H1 (write-once streams were write-allocating
//    77MB/layer through L2, evicting gathered G rows) and NT loads for col.
//  - Accumulator packed as float2 -> v_pk_add_f32.
//  - gemm_scale: NT loads for the read-once A stream (x / H1).
// CSR build (bin_k/build_k), GEMM structure, launch sequence unchanged.
//
// ws layout (bytes):
#define OFF_GCNT 0x0000000   // int[196]     bucket cursors (memset 0)
#define OFF_RP   0x0001000   // int[N+1]     CSR row pointers
#define OFF_DINV 0x0070000   // float[N]     rsqrt(deg+1)
#define OFF_WT1  0x00E0000   // bf16[128*128] W1^T
#define OFF_WT2  0x00E8000   // bf16[128*128] W2^T
#define OFF_COL  0x00F0000   // int[E]       CSR col (src) ids
#define OFF_G    0x0710000   // overlay: gBuf (9.6MB, dead after build_k) then
                             //          bf16 G[N*128] (25.6MB)
#define OFF_H1   0x1F80000   // bf16[N*128]  h1 staged for layer-2 GEMM
#define WS_NEED  0x3800000   // ~58.7MB if H1 used; 33MB min otherwise

#define CAPL   64      // LDS slots per bucket in bin_k
#define MAXNBK 200     // static LDS sizing (actual NBK=196 for N=100000)
#define CAP2   12288   // global slots per bucket (avg fill 8163, +45 sigma)

typedef short bf16x8 __attribute__((ext_vector_type(8)));
typedef float f32x4 __attribute__((ext_vector_type(4)));
typedef float f32x2 __attribute__((ext_vector_type(2)));
typedef unsigned int u32x4 __attribute__((ext_vector_type(4)));

static __device__ __forceinline__ unsigned short f2bf(float f) {
    unsigned int u = __float_as_uint(f);
    u = u + 0x7fffu + ((u >> 16) & 1u);   // round-to-nearest-even
    return (unsigned short)(u >> 16);
}

// ---------- phase 1: LDS-binned edge bucketing ----------
__global__ __launch_bounds__(256) void bin_k(
    const int* __restrict__ src, const int* __restrict__ dst,
    int* __restrict__ gCnt, unsigned* __restrict__ gBuf, int E, int NBK) {
    __shared__ int lcnt[MAXNBK];
    __shared__ unsigned lbuf[MAXNBK * CAPL];
    for (int i = threadIdx.x; i < NBK; i += 256) lcnt[i] = 0;
    __syncthreads();
    int base = blockIdx.x * 4096;
#pragma unroll 4
    for (int j = 0; j < 16; j++) {
        int e = base + j * 256 + threadIdx.x;
        if (e < E) {
            int d = dst[e], s = src[e];
            int b = d >> 9;
            unsigned entry = ((unsigned)(d & 511) << 23) | (unsigned)s;
            int pos = atomicAdd(&lcnt[b], 1);
            if (pos < CAPL) {
                lbuf[b * CAPL + pos] = entry;
            } else {            // overflow spill (statistically never at CAPL=64)
                int gp = atomicAdd(&gCnt[b], 1);
                if (gp < CAP2) gBuf[(size_t)b * CAP2 + gp] = entry;
            }
        }
    }
    __syncthreads();
    for (int b = threadIdx.x; b < NBK; b += 256) {
        int n = lcnt[b]; if (n > CAPL) n = CAPL;
        if (n) {
            int gp = atomicAdd(&gCnt[b], n);
            for (int k = 0; k < n; k++) {
                int p = gp + k;
                if (p < CAP2) gBuf[(size_t)b * CAP2 + p] = lbuf[b * CAPL + k];
            }
        }
    }
}

// ---------- phase 2: per-bucket counting sort -> rp, dinv, col ----------
__global__ __launch_bounds__(256) void build_k(
    const unsigned* __restrict__ gBuf, const int* __restrict__ gCnt,
    int* __restrict__ rp, float* __restrict__ dinv, int* __restrict__ col,
    int NBK, int N) {
    __shared__ unsigned entries[CAP2];
    __shared__ int bc[256], tmp[256];
    __shared__ int ncnt[512], nrp[512], ncur[512];
    int t = threadIdx.x, b = blockIdx.x;

    // scan bucket counts -> colBase
    int c = (t < NBK) ? gCnt[t] : 0;
    if (c > CAP2) c = CAP2;
    bc[t] = c;
    tmp[t] = c;
    __syncthreads();
    for (int off = 1; off < 256; off <<= 1) {
        int x = (t >= off) ? tmp[t - off] : 0;
        __syncthreads(); tmp[t] += x; __syncthreads();
    }
    int colBase = tmp[b] - bc[b];
    int total = tmp[255];
    int cntb = bc[b];
    if (b == 0 && t == 0) rp[N] = total;

    // load this bucket's entries
    for (int k = t; k < cntb; k += 256) entries[k] = gBuf[(size_t)b * CAP2 + k];
    ncnt[t] = 0; ncnt[t + 256] = 0;
    __syncthreads();

    // pass A: per-node counts
    for (int k = t; k < cntb; k += 256) atomicAdd(&ncnt[entries[k] >> 23], 1);
    __syncthreads();

    // exclusive scan of 512 counts with 256 threads
    int v0 = ncnt[2 * t], v1 = ncnt[2 * t + 1];
    int ps = v0 + v1;
    tmp[t] = ps;
    __syncthreads();
    for (int off = 1; off < 256; off <<= 1) {
        int x = (t >= off) ? tmp[t - off] : 0;
        __syncthreads(); tmp[t] += x; __syncthreads();
    }
    int ex = tmp[t] - ps;
    nrp[2 * t] = ex;          ncur[2 * t] = ex;
    nrp[2 * t + 1] = ex + v0; ncur[2 * t + 1] = ex + v0;
    __syncthreads();

    // rp + dinv (coalesced)
    int g0 = b << 9;
    for (int i = t; i < 512; i += 256) {
        int g = g0 + i;
        if (g < N) {
            rp[g] = colBase + nrp[i];
            dinv[g] = rsqrtf((float)(ncnt[i] + 1));
        }
    }
    __syncthreads();

    // pass B: place into col (scatter confined to this bucket's region)
    for (int k = t; k < cntb; k += 256) {
        unsigned e = entries[k];
        int dl = e >> 23;
        int s = (int)(e & 0x7fffffu);
        int pos = atomicAdd(&ncur[dl], 1);
        col[colBase + pos] = s;
    }
}

// ---------- transpose + cvt W (128x128 f32 -> bf16) ----------
__global__ void transpose_w(const float* __restrict__ W,
                            unsigned short* __restrict__ WT) {
    int idx = blockIdx.x * 256 + threadIdx.x;   // grid 64 -> 16384
    int n = idx >> 7, k = idx & 127;
    WT[idx] = f2bf(W[k * 128 + n]);
}

// ---------- GEMM: G[r,:] = bf16( (A[r,:] @ W) * dinv[r] ) ----------
// AF32=1: A is float32 [M,lda]; AF32=0: A is bf16 (ushort) [M,lda]
template <int AF32>
__global__ __launch_bounds__(256) void gemm_scale(
    const void* __restrict__ Av, int lda,
    const unsigned short* __restrict__ WT,
    const float* __restrict__ dinv,
    unsigned short* __restrict__ G, int M) {
    int wave = threadIdx.x >> 6;
    int lane = threadIdx.x & 63;
    int quad = lane >> 4;
    int l16  = lane & 15;
    int rowBase = blockIdx.x * 64 + wave * 16;
    int rowc = rowBase + l16;
    if (rowc > M - 1) rowc = M - 1;

    f32x4 acc[8];
#pragma unroll
    for (int t = 0; t < 8; t++) acc[t] = (f32x4){0.f, 0.f, 0.f, 0.f};

#pragma unroll
    for (int kk = 0; kk < 128; kk += 32) {
        bf16x8 a;
        if (AF32) {
            const float* Af = (const float*)Av;
            const f32x4* ap = (const f32x4*)(Af + (size_t)rowc * lda + kk + quad * 8);
            f32x4 a0 = __builtin_nontemporal_load(ap);
            f32x4 a1 = __builtin_nontemporal_load(ap + 1);
#pragma unroll
            for (int j = 0; j < 4; j++) {
                a[j]     = (short)f2bf(a0[j]);
                a[j + 4] = (short)f2bf(a1[j]);
            }
        } else {
            const unsigned short* Ab = (const unsigned short*)Av;
            a = __builtin_nontemporal_load(
                    (const bf16x8*)(Ab + (size_t)rowc * lda + kk + quad * 8));
        }
#pragma unroll
        for (int t = 0; t < 8; t++) {
            bf16x8 b = *(const bf16x8*)(WT + (t * 16 + l16) * 128 + kk + quad * 8);
            acc[t] = __builtin_amdgcn_mfma_f32_16x16x32_bf16(a, b, acc[t], 0, 0, 0);
        }
    }
    // D layout: row = quad*4 + reg, col = l16 (within each 16x16 tile t)
#pragma unroll
    for (int r = 0; r < 4; r++) {
        int orow = rowBase + quad * 4 + r;
        if (orow < M) {
            float di = dinv[orow];
#pragma unroll
            for (int t = 0; t < 8; t++) {
                G[(size_t)orow * 128 + t * 16 + l16] = f2bf(acc[t][r] * di);
            }
        }
    }
}

// ---------- Aggregate ----------
// out[n,:] = relu(dinv[n]*(g[n,:] + sum_{s in N(n)} g[s,:]) + b)
// One wave per node. lane = 16*g + i: group g processes edge slots g, g+4,
// g+8,... (slot e0-1 = self-loop); lane loads channels [8i, 8i+8) as 16B.
// FOUR slots in flight per group (16 rows/wave): with mean degree 16 the
// whole per-group slot list usually fits one window, so the col->G dependent
// chain runs once per node instead of looping. Invalid slots in a window are
// clamped to row gid (L1-hot: it's the self row) and their accumulate is
// predicated off. Out/H are streamed with non-temporal stores so the 77MB of
// write-once data stops evicting G from L2.
static __device__ __forceinline__ void accum8(f32x2* acc, u32x4 v) {
#pragma unroll
    for (int d = 0; d < 4; d++) {
        f32x2 t;
        t[0] = __uint_as_float(v[d] << 16);
        t[1] = __uint_as_float(v[d] & 0xffff0000u);
        acc[d] += t;                       // v_pk_add_f32
    }
}

__global__ __launch_bounds__(256) void agg_k(
    const unsigned short* __restrict__ G,
    const int* __restrict__ rp, const int* __restrict__ col,
    const float* __restrict__ dinv, const float* __restrict__ bias,
    float* __restrict__ Out, unsigned short* __restrict__ H,
    int colbase, int N) {
    int gid = (blockIdx.x * blockDim.x + threadIdx.x) >> 6;
    if (gid >= N) return;
    int lane = threadIdx.x & 63;
    int g = lane >> 4, i = lane & 15;

    f32x2 acc[4];
#pragma unroll
    for (int j = 0; j < 4; j++) acc[j] = (f32x2){0.f, 0.f};

    int e0 = rp[gid], e1 = rp[gid + 1];
    // virtual slot list: index e0-1 == self, then col[e0..e1).
    // group g owns slots e0-1+g, +4, +8, ... ; window of 4 in flight.
    int my = e0 - 1 + g;
    int c0 = (my < e1) ? ((my >= e0) ? __builtin_nontemporal_load(col + my) : gid)
                       : -1; my += 4;
    int c1 = (my < e1) ? __builtin_nontemporal_load(col + my) : -1; my += 4;
    int c2 = (my < e1) ? __builtin_nontemporal_load(col + my) : -1; my += 4;
    int c3 = (my < e1) ? __builtin_nontemporal_load(col + my) : -1; my += 4;

    const unsigned short* Gi = G + (size_t)i * 8;

    // c0 >= 0 iff the window is non-empty (slots fill in order within a group)
    while (c0 >= 0) {
        int n0 = (my < e1) ? __builtin_nontemporal_load(col + my) : -1; my += 4;
        int n1 = (my < e1) ? __builtin_nontemporal_load(col + my) : -1; my += 4;
        int n2 = (my < e1) ? __builtin_nontemporal_load(col + my) : -1; my += 4;
        int n3 = (my < e1) ? __builtin_nontemporal_load(col + my) : -1; my += 4;
        // clamp invalid slots to the (L1-hot) self row so all 4 loads issue
        // unconditionally and stay in flight together
        int a1 = (c1 >= 0) ? c1 : gid;
        int a2 = (c2 >= 0) ? c2 : gid;
        int a3 = (c3 >= 0) ? c3 : gid;
        u32x4 v0 = *(const u32x4*)(Gi + (size_t)c0 * 128);
        u32x4 v1 = *(const u32x4*)(Gi + (size_t)a1 * 128);
        u32x4 v2 = *(const u32x4*)(Gi + (size_t)a2 * 128);
        u32x4 v3 = *(const u32x4*)(Gi + (size_t)a3 * 128);
        accum8(acc, v0);
        if (c1 >= 0) accum8(acc, v1);
        if (c2 >= 0) accum8(acc, v2);
        if (c3 >= 0) accum8(acc, v3);
        c0 = n0; c1 = n1; c2 = n2; c3 = n3;
    }

    // combine the 4 groups
    float a8[8];
#pragma unroll
    for (int d = 0; d < 4; d++) { a8[2 * d] = acc[d][0]; a8[2 * d + 1] = acc[d][1]; }
#pragma unroll
    for (int j = 0; j < 8; j++) a8[j] += __shfl_xor(a8[j], 16, 64);
#pragma unroll
    for (int j = 0; j < 8; j++) a8[j] += __shfl_xor(a8[j], 32, 64);

    if (g == 0) {
        float di = dinv[gid];
        const f32x4* bp = (const f32x4*)(bias + i * 8);
        f32x4 b0 = bp[0], b1 = bp[1];
        f32x4 o0, o1;
#pragma unroll
        for (int j = 0; j < 4; j++) {
            o0[j] = fmaxf(a8[j] * di + b0[j], 0.f);
            o1[j] = fmaxf(a8[j + 4] * di + b1[j], 0.f);
        }
        float* orow = Out + (size_t)gid * 256 + colbase + i * 8;
        __builtin_nontemporal_store(o0, (f32x4*)orow);
        __builtin_nontemporal_store(o1, (f32x4*)(orow + 4));
        if (H) {
            bf16x8 hv;
#pragma unroll
            for (int j = 0; j < 4; j++) {
                hv[j]     = (short)f2bf(o0[j]);
                hv[j + 4] = (short)f2bf(o1[j]);
            }
            __builtin_nontemporal_store(hv, (bf16x8*)(H + (size_t)gid * 128 + i * 8));
        }
    }
}

extern "C" void kernel_launch(void* const* d_in, const int* in_sizes, int n_in,
                              void* d_out, int out_size, void* d_ws, size_t ws_size,
                              hipStream_t stream) {
    const float* x  = (const float*)d_in[0];   // [N,128] f32
    const float* W1 = (const float*)d_in[1];   // [128,128] f32
    const float* b1 = (const float*)d_in[2];   // [128] f32
    const float* W2 = (const float*)d_in[3];
    const float* b2 = (const float*)d_in[4];
    const int* ei = (const int*)d_in[5];       // [2,E] int32

    const int N = in_sizes[0] / 128;
    const int E = in_sizes[5] / 2;
    const int* src = ei;
    const int* dst = ei + E;
    const int NBK = (N + 511) >> 9;            // 196 for N=100000 (<= MAXNBK)

    char* ws = (char*)d_ws;
    int*      gCnt = (int*)(ws + OFF_GCNT);
    int*      rp   = (int*)(ws + OFF_RP);
    float*    dinv = (float*)(ws + OFF_DINV);
    unsigned short* WT1 = (unsigned short*)(ws + OFF_WT1);
    unsigned short* WT2 = (unsigned short*)(ws + OFF_WT2);
    int*      col  = (int*)(ws + OFF_COL);
    unsigned* gBuf = (unsigned*)(ws + OFF_G);          // dead after build_k
    unsigned short* G = (unsigned short*)(ws + OFF_G); // overlays gBuf
    unsigned short* H1 = (ws_size >= (size_t)WS_NEED)
                         ? (unsigned short*)(ws + OFF_H1) : nullptr;
    float* out = (float*)d_out;

    hipMemsetAsync(gCnt, 0, (size_t)NBK * sizeof(int), stream);

    transpose_w<<<64, 256, 0, stream>>>(W1, WT1);
    transpose_w<<<64, 256, 0, stream>>>(W2, WT2);

    // CSR build: bin then per-bucket counting sort
    bin_k<<<(E + 4095) / 4096, 256, 0, stream>>>(src, dst, gCnt, gBuf, E, NBK);
    build_k<<<NBK, 256, 0, stream>>>(gBuf, gCnt, rp, dinv, col, NBK, N);

    int gb = (N + 63) / 64;
    int ab = (N + 3) / 4;

    // Layer 1 (A = x, f32)
    gemm_scale<1><<<gb, 256, 0, stream>>>(x, 128, WT1, dinv, G, N);
    agg_k<<<ab, 256, 0, stream>>>(G, rp, col, dinv, b1, out, H1, 0, N);
    // Layer 2 (A = h1: bf16 H1 if scratch allows, else f32 rows of out)
    if (H1) {
        gemm_scale<0><<<gb, 256, 0, stream>>>(H1, 128, WT2, dinv, G, N);
    } else {
        gemm_scale<1><<<gb, 256, 0, stream>>>(out, 256, WT2, dinv, G, N);
    }
    agg_k<<<ab, 256, 0, stream>>>(G, rp, col, dinv, b2, out, nullptr, 128, N);
}